// Round 3
// baseline (1147.504 us; speedup 1.0000x reference)
//
#include <hip/hip_runtime.h>
#include <stdint.h>

using bf16   = __bf16;
using bf16x4 = __attribute__((ext_vector_type(4))) __bf16;
using bf16x8 = __attribute__((ext_vector_type(8))) __bf16;
using f32x4  = __attribute__((ext_vector_type(4))) float;

#define DEV_INLINE __device__ __forceinline__

// async global->LDS, 16B per lane. LDS base must be wave-uniform; HW adds lane*16.
DEV_INLINE void gload16(const void* g, const void* l) {
  __builtin_amdgcn_global_load_lds(
      (const __attribute__((address_space(1))) unsigned int*)(uintptr_t)g,
      (__attribute__((address_space(3))) unsigned int*)(unsigned int)(uintptr_t)l,
      16, 0, 0);
}

DEV_INLINE f32x4 mfma16(bf16x8 a, bf16x8 b, f32x4 c) {
  return __builtin_amdgcn_mfma_f32_16x16x32_bf16(a, b, c, 0, 0, 0);
}

// ---------------- cast x (fp32 -> bf16) ----------------
__global__ void cast_f32_bf16(const float4* __restrict__ in, bf16* __restrict__ out, int n4) {
  int i = blockIdx.x * 256 + threadIdx.x;
  if (i >= n4) return;
  float4 v = in[i];
  bf16x4 o = { (bf16)v.x, (bf16)v.y, (bf16)v.z, (bf16)v.w };
  *(bf16x4*)(out + (size_t)i * 4) = o;
}

// ---------------- transpose+cast: in [rows][cols] f32 -> out [cols][rows] bf16 ----
__global__ void transpose_cast(const float* __restrict__ in, bf16* __restrict__ out,
                               int rows, int cols) {
  __shared__ float tile[32][33];
  int c0 = blockIdx.x * 32, r0 = blockIdx.y * 32;
  int t = threadIdx.x, tc = t & 31, tr = t >> 5;
  for (int i = 0; i < 4; ++i)
    tile[tr + i*8][tc] = in[(size_t)(r0 + tr + i*8) * cols + (c0 + tc)];
  __syncthreads();
  for (int i = 0; i < 4; ++i)
    out[(size_t)(c0 + tr + i*8) * rows + (r0 + tc)] = (bf16)tile[tc][tr + i*8];
}

// ---------------- GEMM: C[M][N] = A[M][K] * Bt[N][K]^T, bf16 in, fp32 acc ------
template<bool OUT_BF16>
__global__ __launch_bounds__(256)
void gemm_bt(const bf16* __restrict__ A, const bf16* __restrict__ Bt,
             void* __restrict__ Cout, int M, int N, int K) {
  __shared__ bf16 sA[16 * 512];   // 16KB
  __shared__ bf16 sB[16 * 512];   // 16KB
  int tid = threadIdx.x;
  int w = tid >> 6, l = tid & 63, lr = l & 15, lc = l >> 4;
  int bn0 = blockIdx.x * 128, bm0 = blockIdx.y * 128;
  int wm = (w & 1) * 4, wn = (w >> 1) * 4;   // units of 16-wide tiles
  const bf16* Ab = A  + (size_t)bm0 * K;
  const bf16* Bb = Bt + (size_t)bn0 * K;
  f32x4 acc[4][4] = {};
  for (int k0 = 0; k0 < K; k0 += 64) {
    __syncthreads();
    for (int i = 0; i < 4; ++i) {
      int id = w * 4 + i;
      int mt = id >> 1, ks = id & 1;
      gload16(Ab + (size_t)(mt*16 + lr) * K + (k0 + ks*32 + lc*8), sA + id * 512);
      gload16(Bb + (size_t)(mt*16 + lr) * K + (k0 + ks*32 + lc*8), sB + id * 512);
    }
    __syncthreads();
    for (int ks = 0; ks < 2; ++ks) {
      bf16x8 af[4], bfr[4];
      for (int i = 0; i < 4; ++i)
        af[i]  = *(const bf16x8*)(sA + ((wm + i)*2 + ks) * 512 + l*8);
      for (int j = 0; j < 4; ++j)
        bfr[j] = *(const bf16x8*)(sB + ((wn + j)*2 + ks) * 512 + l*8);
      for (int i = 0; i < 4; ++i)
        for (int j = 0; j < 4; ++j)
          acc[i][j] = mfma16(af[i], bfr[j], acc[i][j]);
    }
  }
  // C/D layout: row = lc*4 + reg, col = lr  (m89-verified)
  int wrow = bm0 + wm*16, wcol = bn0 + wn*16;
  for (int i = 0; i < 4; ++i)
    for (int j = 0; j < 4; ++j)
      for (int r = 0; r < 4; ++r) {
        size_t idx = (size_t)(wrow + i*16 + lc*4 + r) * N + (wcol + j*16 + lr);
        if (OUT_BF16) ((bf16*)Cout)[idx] = (bf16)acc[i][j][r];
        else          ((float*)Cout)[idx] = acc[i][j][r];
      }
}

// ---------------- RoPE + scatter to attention layouts ----------------
// QKV row = [Q(16*128) | K(8*128) | V(8*128)], per (b,s).
// Q gets (1/sqrt(HD)) * log2(e) folded in so attention can use exp2 directly.
__global__ void rope_kernel(const bf16* __restrict__ QKV, const float* __restrict__ cs,
                            const float* __restrict__ sn, bf16* __restrict__ Q,
                            bf16* __restrict__ K) {
  int row = blockIdx.x;               // b*2048 + s
  int b = row >> 11, s = row & 2047;
  const bf16* src = QKV + (size_t)row * 4096;
  const float* cr = cs + (size_t)s * 128;
  const float* sr = sn + (size_t)s * 128;
  const float qscale = 0.08838834764831845f * 1.4426950408889634f;  // log2e/sqrt(128)
  for (int i = threadIdx.x; i < 1536; i += 256) {
    if (i < 1024) {            // Q pairs
      int h = i >> 6, d = i & 63;
      float v0 = (float)src[h*128 + d];
      float v1 = (float)src[h*128 + d + 64];
      bf16* dst = Q + ((size_t)(b*16 + h) * 2048 + s) * 128;
      dst[d]      = (bf16)((v0*cr[d]      - v1*sr[d])      * qscale);
      dst[d + 64] = (bf16)((v1*cr[d + 64] + v0*sr[d + 64]) * qscale);
    } else {                   // K pairs
      int j = i - 1024;
      int h = j >> 6, d = j & 63;
      float v0 = (float)src[2048 + h*128 + d];
      float v1 = (float)src[2048 + h*128 + d + 64];
      bf16* dst = K + ((size_t)(b*8 + h) * 2048 + s) * 128;
      dst[d]      = (bf16)(v0*cr[d]      - v1*sr[d]);
      dst[d + 64] = (bf16)(v1*cr[d + 64] + v0*sr[d + 64]);
    }
  }
}

// ---------------- V transpose: QKV v-part -> Vt[b*8+h][d][s] ----------------
__global__ void v_transpose(const bf16* __restrict__ QKV, bf16* __restrict__ Vt) {
  __shared__ bf16 tile[32][33];
  int s0 = blockIdx.x * 32, d0 = blockIdx.y * 32, bh = blockIdx.z;
  int b = bh >> 3, h = bh & 7;
  int t = threadIdx.x, tc = t & 31, tr = t >> 5;
  for (int i = 0; i < 4; ++i)
    tile[tr + i*8][tc] =
        QKV[((size_t)(b*2048) + s0 + tr + i*8) * 4096 + 3072 + h*128 + d0 + tc];
  __syncthreads();
  for (int i = 0; i < 4; ++i)
    Vt[((size_t)bh * 128 + d0 + tr + i*8) * 2048 + s0 + tc] = tile[tc][tr + i*8];
}

// ---------------- flash attention, causal, GQA-fused ----------------
// block = 4 waves; one block handles BOTH q-heads of one kv-head (K/V staged
// once, used twice). BM=64 q rows (16/wave), BN=64 keys/tile, HD=128.
// No-running-max softmax (exp2 domain, log2e folded into Q), deferred l
// reduction, XOR-swizzled P layout. LPT: qi = 31 - blockIdx.x.
__global__ __launch_bounds__(256, 3)
void attn_kernel(const bf16* __restrict__ Q, const bf16* __restrict__ Kg,
                 const bf16* __restrict__ Vt, bf16* __restrict__ Og) {
  __shared__ bf16 sK[16 * 512];    // 16KB: chunks (nt 0..3)x(ks 0..3)
  __shared__ bf16 sV[16 * 512];    // 16KB: chunks (ntd 0..7)x(ksk 0..1)
  __shared__ bf16 sP0[4 * 1024];   // 8KB: head0 P, per-wave, XOR swizzle
  __shared__ bf16 sP1[4 * 1024];   // 8KB: head1 P
  int qi = 31 - blockIdx.x;        // LPT: longest first
  int bkv = blockIdx.y;            // b*8 + kvh
  int b = bkv >> 3, kvh = bkv & 7;
  int tid = threadIdx.x, w = tid >> 6, l = tid & 63, lr = l & 15, lc = l >> 4;
  const bf16* Qb0 = Q + ((size_t)(b*16 + kvh*2) * 2048 + qi*64) * 128;
  const bf16* Qb1 = Qb0 + (size_t)2048 * 128;
  const bf16* Kb  = Kg + (size_t)bkv * 2048 * 128;
  const bf16* Vb  = Vt + (size_t)bkv * 128 * 2048;
  bf16x8 qf0[4], qf1[4];
  for (int ks = 0; ks < 4; ++ks) {
    size_t off = (size_t)(w*16 + lr) * 128 + ks*32 + lc*8;
    qf0[ks] = *(const bf16x8*)(Qb0 + off);
    qf1[ks] = *(const bf16x8*)(Qb1 + off);
  }
  f32x4 o0[8] = {}, o1[8] = {};
  float l0[4] = {0.f,0.f,0.f,0.f}, l1[4] = {0.f,0.f,0.f,0.f};
  int qrow = qi*64 + w*16 + lc*4;      // + r
  bf16* sPw0 = sP0 + w * 1024;
  bf16* sPw1 = sP1 + w * 1024;
  for (int t = 0; t <= qi; ++t) {
    __syncthreads();
    for (int i = 0; i < 4; ++i) {
      int id = w*4 + i;
      { int nt = id >> 2, ks = id & 3;
        gload16(Kb + (size_t)(t*64 + nt*16 + lr) * 128 + ks*32 + lc*8, sK + id*512); }
      { int nt = id >> 1, ks = id & 1;
        gload16(Vb + (size_t)(nt*16 + lr) * 2048 + t*64 + ks*32 + lc*8, sV + id*512); }
    }
    __syncthreads();
    // S = Q K^T for both heads; K fragments loaded once
    f32x4 s0[4] = {}, s1[4] = {};
    for (int nt = 0; nt < 4; ++nt)
      for (int ks = 0; ks < 4; ++ks) {
        bf16x8 kf = *(const bf16x8*)(sK + (nt*4 + ks)*512 + l*8);
        s0[nt] = mfma16(qf0[ks], kf, s0[nt]);
        s1[nt] = mfma16(qf1[ks], kf, s1[nt]);
      }
    // causal mask: only the diagonal tile (block-uniform branch)
    if (t == qi) {
      for (int nt = 0; nt < 4; ++nt) {
        int col = t*64 + nt*16 + lr;
        for (int r = 0; r < 4; ++r)
          if (col > qrow + r) { s0[nt][r] = -1e30f; s1[nt][r] = -1e30f; }
      }
    }
    // p = exp2(s); per-lane l partials; swizzled P write:
    // addr = q*64 + ((key>>3) ^ (q&7))*8 + (key&7)
    for (int nt = 0; nt < 4; ++nt) {
      int blk = nt*2 + (lr >> 3);
      int off = lr & 7;
      for (int r = 0; r < 4; ++r) {
        int q = lc*4 + r;
        int addr = q*64 + ((blk ^ (q & 7)) * 8) + off;
        float p0 = __builtin_amdgcn_exp2f(s0[nt][r]);
        l0[r] += p0;
        sPw0[addr] = (bf16)p0;
        float p1 = __builtin_amdgcn_exp2f(s1[nt][r]);
        l1[r] += p1;
        sPw1[addr] = (bf16)p1;
      }
    }
    asm volatile("s_waitcnt lgkmcnt(0)" ::: "memory");  // wave-private P: no barrier
    bf16x8 pf0[2], pf1[2];
    for (int ks = 0; ks < 2; ++ks) {
      int addr = lr*64 + (((ks*4 + lc) ^ (lr & 7)) * 8);
      pf0[ks] = *(const bf16x8*)(sPw0 + addr);
      pf1[ks] = *(const bf16x8*)(sPw1 + addr);
    }
    for (int nt = 0; nt < 8; ++nt)
      for (int ks = 0; ks < 2; ++ks) {
        bf16x8 vf = *(const bf16x8*)(sV + (nt*2 + ks)*512 + l*8);
        o0[nt] = mfma16(pf0[ks], vf, o0[nt]);
        o1[nt] = mfma16(pf1[ks], vf, o1[nt]);
      }
  }
  // deferred l reduction: one shuffle ladder for the whole kernel
  for (int msk = 1; msk < 16; msk <<= 1)
    for (int r = 0; r < 4; ++r) {
      l0[r] += __shfl_xor(l0[r], msk, 64);
      l1[r] += __shfl_xor(l1[r], msk, 64);
    }
  for (int r = 0; r < 4; ++r) {
    float inv0 = 1.f / l0[r];
    float inv1 = 1.f / l1[r];
    size_t row = (size_t)(b*2048) + qi*64 + w*16 + lc*4 + r;
    size_t base0 = row * 2048 + (kvh*2) * 128;
    for (int nt = 0; nt < 8; ++nt) {
      Og[base0 + nt*16 + lr]       = (bf16)(o0[nt][r] * inv0);
      Og[base0 + 128 + nt*16 + lr] = (bf16)(o1[nt][r] * inv1);
    }
  }
}

extern "C" void kernel_launch(void* const* d_in, const int* in_sizes, int n_in,
                              void* d_out, int out_size, void* d_ws, size_t ws_size,
                              hipStream_t stream) {
  (void)in_sizes; (void)n_in; (void)out_size; (void)ws_size;
  const float* x  = (const float*)d_in[0];
  const float* cs = (const float*)d_in[1];
  const float* sn = (const float*)d_in[2];
  const float* Wq = (const float*)d_in[3];
  const float* Wk = (const float*)d_in[4];
  const float* Wv = (const float*)d_in[5];
  const float* Wo = (const float*)d_in[6];
  float* out = (float*)d_out;

  char* p = (char*)d_ws;
  bf16* xb    = (bf16*)p;  p += (size_t)8192*2048*2;    // x bf16
  bf16* Wt    = (bf16*)p;  p += (size_t)4096*2048*2;    // [Wq|Wk|Wv]^T bf16
  bf16* Wot   = (bf16*)p;  p += (size_t)2048*2048*2;    // Wo^T bf16
  bf16* QKV   = (bf16*)p;  p += (size_t)8192*4096*2;    // projections
  bf16* Qr    = (bf16*)p;  p += (size_t)64*2048*128*2;  // Q roped [bh][s][d]
  bf16* Kr    = (bf16*)p;  p += (size_t)32*2048*128*2;  // K roped [bkv][s][d]
  bf16* Vtb   = (bf16*)p;  p += (size_t)32*2048*128*2;  // V^T [bkv][d][s]
  bf16* attnb = (bf16*)p;  p += (size_t)8192*2048*2;    // attention out

  cast_f32_bf16<<<4194304/256, 256, 0, stream>>>((const float4*)x, xb, 4194304);
  transpose_cast<<<dim3(64,64), 256, 0, stream>>>(Wq, Wt, 2048, 2048);
  transpose_cast<<<dim3(32,64), 256, 0, stream>>>(Wk, Wt + (size_t)2048*2048, 2048, 1024);
  transpose_cast<<<dim3(32,64), 256, 0, stream>>>(Wv, Wt + (size_t)3072*2048, 2048, 1024);
  transpose_cast<<<dim3(64,64), 256, 0, stream>>>(Wo, Wot, 2048, 2048);
  gemm_bt<true ><<<dim3(32,64), 256, 0, stream>>>(xb, Wt, QKV, 8192, 4096, 2048);
  rope_kernel<<<8192, 256, 0, stream>>>(QKV, cs, sn, Qr, Kr);
  v_transpose<<<dim3(64,4,32), 256, 0, stream>>>(QKV, Vtb);
  attn_kernel<<<dim3(32,32), 256, 0, stream>>>(Qr, Kr, Vtb, attnb);
  gemm_bt<false><<<dim3(16,64), 256, 0, stream>>>(attnb, Wot, out, 8192, 2048, 2048);
}

// Round 4
// 748.685 us; speedup vs baseline: 1.5327x; 1.5327x over previous
//
#include <hip/hip_runtime.h>
#include <stdint.h>

using bf16   = __bf16;
using bf16x4 = __attribute__((ext_vector_type(4))) __bf16;
using bf16x8 = __attribute__((ext_vector_type(8))) __bf16;
using f32x4  = __attribute__((ext_vector_type(4))) float;

#define DEV_INLINE __device__ __forceinline__

// async global->LDS, 16B per lane. LDS base must be wave-uniform; HW adds lane*16.
DEV_INLINE void gload16(const void* g, const void* l) {
  __builtin_amdgcn_global_load_lds(
      (const __attribute__((address_space(1))) unsigned int*)(uintptr_t)g,
      (__attribute__((address_space(3))) unsigned int*)(unsigned int)(uintptr_t)l,
      16, 0, 0);
}

DEV_INLINE f32x4 mfma16(bf16x8 a, bf16x8 b, f32x4 c) {
  return __builtin_amdgcn_mfma_f32_16x16x32_bf16(a, b, c, 0, 0, 0);
}

// ---------------- cast x (fp32 -> bf16) ----------------
__global__ void cast_f32_bf16(const float4* __restrict__ in, bf16* __restrict__ out, int n4) {
  int i = blockIdx.x * 256 + threadIdx.x;
  if (i >= n4) return;
  float4 v = in[i];
  bf16x4 o = { (bf16)v.x, (bf16)v.y, (bf16)v.z, (bf16)v.w };
  *(bf16x4*)(out + (size_t)i * 4) = o;
}

// ---------------- transpose+cast: in [rows][cols] f32 -> out [cols][rows] bf16 ----
__global__ void transpose_cast(const float* __restrict__ in, bf16* __restrict__ out,
                               int rows, int cols) {
  __shared__ float tile[32][33];
  int c0 = blockIdx.x * 32, r0 = blockIdx.y * 32;
  int t = threadIdx.x, tc = t & 31, tr = t >> 5;
  for (int i = 0; i < 4; ++i)
    tile[tr + i*8][tc] = in[(size_t)(r0 + tr + i*8) * cols + (c0 + tc)];
  __syncthreads();
  for (int i = 0; i < 4; ++i)
    out[(size_t)(c0 + tr + i*8) * rows + (r0 + tc)] = (bf16)tile[tc][tr + i*8];
}

// ---------------- GEMM: C[M][N] = A[M][K] * Bt[N][K]^T, bf16 in, fp32 acc ------
template<bool OUT_BF16>
__global__ __launch_bounds__(256)
void gemm_bt(const bf16* __restrict__ A, const bf16* __restrict__ Bt,
             void* __restrict__ Cout, int M, int N, int K) {
  __shared__ bf16 sA[16 * 512];   // 16KB
  __shared__ bf16 sB[16 * 512];   // 16KB
  int tid = threadIdx.x;
  int w = tid >> 6, l = tid & 63, lr = l & 15, lc = l >> 4;
  int bn0 = blockIdx.x * 128, bm0 = blockIdx.y * 128;
  int wm = (w & 1) * 4, wn = (w >> 1) * 4;   // units of 16-wide tiles
  const bf16* Ab = A  + (size_t)bm0 * K;
  const bf16* Bb = Bt + (size_t)bn0 * K;
  f32x4 acc[4][4] = {};
  for (int k0 = 0; k0 < K; k0 += 64) {
    __syncthreads();
    for (int i = 0; i < 4; ++i) {
      int id = w * 4 + i;
      int mt = id >> 1, ks = id & 1;
      gload16(Ab + (size_t)(mt*16 + lr) * K + (k0 + ks*32 + lc*8), sA + id * 512);
      gload16(Bb + (size_t)(mt*16 + lr) * K + (k0 + ks*32 + lc*8), sB + id * 512);
    }
    __syncthreads();
    for (int ks = 0; ks < 2; ++ks) {
      bf16x8 af[4], bfr[4];
      for (int i = 0; i < 4; ++i)
        af[i]  = *(const bf16x8*)(sA + ((wm + i)*2 + ks) * 512 + l*8);
      for (int j = 0; j < 4; ++j)
        bfr[j] = *(const bf16x8*)(sB + ((wn + j)*2 + ks) * 512 + l*8);
      for (int i = 0; i < 4; ++i)
        for (int j = 0; j < 4; ++j)
          acc[i][j] = mfma16(af[i], bfr[j], acc[i][j]);
    }
  }
  // C/D layout: row = lc*4 + reg, col = lr  (m89-verified)
  int wrow = bm0 + wm*16, wcol = bn0 + wn*16;
  for (int i = 0; i < 4; ++i)
    for (int j = 0; j < 4; ++j)
      for (int r = 0; r < 4; ++r) {
        size_t idx = (size_t)(wrow + i*16 + lc*4 + r) * N + (wcol + j*16 + lr);
        if (OUT_BF16) ((bf16*)Cout)[idx] = (bf16)acc[i][j][r];
        else          ((float*)Cout)[idx] = acc[i][j][r];
      }
}

// ---------------- RoPE + scatter to attention layouts ----------------
// QKV row = [Q(16*128) | K(8*128) | V(8*128)], per (b,s).
// Q gets (1/sqrt(HD)) * log2(e) folded in so attention can use exp2 directly.
__global__ void rope_kernel(const bf16* __restrict__ QKV, const float* __restrict__ cs,
                            const float* __restrict__ sn, bf16* __restrict__ Q,
                            bf16* __restrict__ K) {
  int row = blockIdx.x;               // b*2048 + s
  int b = row >> 11, s = row & 2047;
  const bf16* src = QKV + (size_t)row * 4096;
  const float* cr = cs + (size_t)s * 128;
  const float* sr = sn + (size_t)s * 128;
  const float qscale = 0.08838834764831845f * 1.4426950408889634f;  // log2e/sqrt(128)
  for (int i = threadIdx.x; i < 1536; i += 256) {
    if (i < 1024) {            // Q pairs
      int h = i >> 6, d = i & 63;
      float v0 = (float)src[h*128 + d];
      float v1 = (float)src[h*128 + d + 64];
      bf16* dst = Q + ((size_t)(b*16 + h) * 2048 + s) * 128;
      dst[d]      = (bf16)((v0*cr[d]      - v1*sr[d])      * qscale);
      dst[d + 64] = (bf16)((v1*cr[d + 64] + v0*sr[d + 64]) * qscale);
    } else {                   // K pairs
      int j = i - 1024;
      int h = j >> 6, d = j & 63;
      float v0 = (float)src[2048 + h*128 + d];
      float v1 = (float)src[2048 + h*128 + d + 64];
      bf16* dst = K + ((size_t)(b*8 + h) * 2048 + s) * 128;
      dst[d]      = (bf16)(v0*cr[d]      - v1*sr[d]);
      dst[d + 64] = (bf16)(v1*cr[d + 64] + v0*sr[d + 64]);
    }
  }
}

// ---------------- V transpose: QKV v-part -> Vt[b*8+h][d][s] ----------------
__global__ void v_transpose(const bf16* __restrict__ QKV, bf16* __restrict__ Vt) {
  __shared__ bf16 tile[32][33];
  int s0 = blockIdx.x * 32, d0 = blockIdx.y * 32, bh = blockIdx.z;
  int b = bh >> 3, h = bh & 7;
  int t = threadIdx.x, tc = t & 31, tr = t >> 5;
  for (int i = 0; i < 4; ++i)
    tile[tr + i*8][tc] =
        QKV[((size_t)(b*2048) + s0 + tr + i*8) * 4096 + 3072 + h*128 + d0 + tc];
  __syncthreads();
  for (int i = 0; i < 4; ++i)
    Vt[((size_t)bh * 128 + d0 + tr + i*8) * 2048 + s0 + tc] = tile[tc][tr + i*8];
}

// ---------------- flash attention, causal, GQA-fused ----------------
// block = 4 waves; one block handles BOTH q-heads of one kv-head (K/V staged
// once, used twice). BM=64 q rows (16/wave), BN=64 keys/tile, HD=128.
// __launch_bounds__(256, 2): ~150 live regs incl. accs — min-3-waves bound
// caused 213MB of scratch spill traffic (round 3); 2 waves/SIMD fits spill-free.
__global__ __launch_bounds__(256, 2)
void attn_kernel(const bf16* __restrict__ Q, const bf16* __restrict__ Kg,
                 const bf16* __restrict__ Vt, bf16* __restrict__ Og) {
  __shared__ bf16 sK[16 * 512];    // 16KB: chunks (nt 0..3)x(ks 0..3)
  __shared__ bf16 sV[16 * 512];    // 16KB: chunks (ntd 0..7)x(ksk 0..1)
  __shared__ bf16 sP0[4 * 1024];   // 8KB: head0 P, per-wave, XOR swizzle
  __shared__ bf16 sP1[4 * 1024];   // 8KB: head1 P
  int qi = 31 - blockIdx.x;        // LPT: longest first
  int bkv = blockIdx.y;            // b*8 + kvh
  int b = bkv >> 3, kvh = bkv & 7;
  int tid = threadIdx.x, w = tid >> 6, l = tid & 63, lr = l & 15, lc = l >> 4;
  const bf16* Qb0 = Q + ((size_t)(b*16 + kvh*2) * 2048 + qi*64) * 128;
  const bf16* Qb1 = Qb0 + (size_t)2048 * 128;
  const bf16* Kb  = Kg + (size_t)bkv * 2048 * 128;
  const bf16* Vb  = Vt + (size_t)bkv * 128 * 2048;
  bf16x8 qf0[4], qf1[4];
  for (int ks = 0; ks < 4; ++ks) {
    size_t off = (size_t)(w*16 + lr) * 128 + ks*32 + lc*8;
    qf0[ks] = *(const bf16x8*)(Qb0 + off);
    qf1[ks] = *(const bf16x8*)(Qb1 + off);
  }
  f32x4 o0[8] = {}, o1[8] = {};
  float l0[4] = {0.f,0.f,0.f,0.f}, l1[4] = {0.f,0.f,0.f,0.f};
  int qrow = qi*64 + w*16 + lc*4;      // + r
  bf16* sPw0 = sP0 + w * 1024;
  bf16* sPw1 = sP1 + w * 1024;
  for (int t = 0; t <= qi; ++t) {
    __syncthreads();
    for (int i = 0; i < 4; ++i) {
      int id = w*4 + i;
      { int nt = id >> 2, ks = id & 3;
        gload16(Kb + (size_t)(t*64 + nt*16 + lr) * 128 + ks*32 + lc*8, sK + id*512); }
      { int nt = id >> 1, ks = id & 1;
        gload16(Vb + (size_t)(nt*16 + lr) * 2048 + t*64 + ks*32 + lc*8, sV + id*512); }
    }
    __syncthreads();
    // S = Q K^T for both heads; K fragments loaded once
    f32x4 s0[4] = {}, s1[4] = {};
    for (int nt = 0; nt < 4; ++nt)
      for (int ks = 0; ks < 4; ++ks) {
        bf16x8 kf = *(const bf16x8*)(sK + (nt*4 + ks)*512 + l*8);
        s0[nt] = mfma16(qf0[ks], kf, s0[nt]);
        s1[nt] = mfma16(qf1[ks], kf, s1[nt]);
      }
    // causal mask: only the diagonal tile (block-uniform branch)
    if (t == qi) {
      for (int nt = 0; nt < 4; ++nt) {
        int col = t*64 + nt*16 + lr;
        for (int r = 0; r < 4; ++r)
          if (col > qrow + r) { s0[nt][r] = -1e30f; s1[nt][r] = -1e30f; }
      }
    }
    // p = exp2(s); per-lane l partials; swizzled P write:
    // addr = q*64 + ((key>>3) ^ (q&7))*8 + (key&7)
    for (int nt = 0; nt < 4; ++nt) {
      int blk = nt*2 + (lr >> 3);
      int off = lr & 7;
      for (int r = 0; r < 4; ++r) {
        int q = lc*4 + r;
        int addr = q*64 + ((blk ^ (q & 7)) * 8) + off;
        float p0 = __builtin_amdgcn_exp2f(s0[nt][r]);
        l0[r] += p0;
        sPw0[addr] = (bf16)p0;
        float p1 = __builtin_amdgcn_exp2f(s1[nt][r]);
        l1[r] += p1;
        sPw1[addr] = (bf16)p1;
      }
    }
    asm volatile("s_waitcnt lgkmcnt(0)" ::: "memory");  // wave-private P: no barrier
    bf16x8 pf0[2], pf1[2];
    for (int ks = 0; ks < 2; ++ks) {
      int addr = lr*64 + (((ks*4 + lc) ^ (lr & 7)) * 8);
      pf0[ks] = *(const bf16x8*)(sPw0 + addr);
      pf1[ks] = *(const bf16x8*)(sPw1 + addr);
    }
    for (int nt = 0; nt < 8; ++nt)
      for (int ks = 0; ks < 2; ++ks) {
        bf16x8 vf = *(const bf16x8*)(sV + (nt*2 + ks)*512 + l*8);
        o0[nt] = mfma16(pf0[ks], vf, o0[nt]);
        o1[nt] = mfma16(pf1[ks], vf, o1[nt]);
      }
  }
  // deferred l reduction: one shuffle ladder for the whole kernel
  for (int msk = 1; msk < 16; msk <<= 1)
    for (int r = 0; r < 4; ++r) {
      l0[r] += __shfl_xor(l0[r], msk, 64);
      l1[r] += __shfl_xor(l1[r], msk, 64);
    }
  for (int r = 0; r < 4; ++r) {
    float inv0 = 1.f / l0[r];
    float inv1 = 1.f / l1[r];
    size_t row = (size_t)(b*2048) + qi*64 + w*16 + lc*4 + r;
    size_t base0 = row * 2048 + (kvh*2) * 128;
    for (int nt = 0; nt < 8; ++nt) {
      Og[base0 + nt*16 + lr]       = (bf16)(o0[nt][r] * inv0);
      Og[base0 + 128 + nt*16 + lr] = (bf16)(o1[nt][r] * inv1);
    }
  }
}

extern "C" void kernel_launch(void* const* d_in, const int* in_sizes, int n_in,
                              void* d_out, int out_size, void* d_ws, size_t ws_size,
                              hipStream_t stream) {
  (void)in_sizes; (void)n_in; (void)out_size; (void)ws_size;
  const float* x  = (const float*)d_in[0];
  const float* cs = (const float*)d_in[1];
  const float* sn = (const float*)d_in[2];
  const float* Wq = (const float*)d_in[3];
  const float* Wk = (const float*)d_in[4];
  const float* Wv = (const float*)d_in[5];
  const float* Wo = (const float*)d_in[6];
  float* out = (float*)d_out;

  char* p = (char*)d_ws;
  bf16* xb    = (bf16*)p;  p += (size_t)8192*2048*2;    // x bf16
  bf16* Wt    = (bf16*)p;  p += (size_t)4096*2048*2;    // [Wq|Wk|Wv]^T bf16
  bf16* Wot   = (bf16*)p;  p += (size_t)2048*2048*2;    // Wo^T bf16
  bf16* QKV   = (bf16*)p;  p += (size_t)8192*4096*2;    // projections
  bf16* Qr    = (bf16*)p;  p += (size_t)64*2048*128*2;  // Q roped [bh][s][d]
  bf16* Kr    = (bf16*)p;  p += (size_t)32*2048*128*2;  // K roped [bkv][s][d]
  bf16* Vtb   = (bf16*)p;  p += (size_t)32*2048*128*2;  // V^T [bkv][d][s]
  bf16* attnb = (bf16*)p;  p += (size_t)8192*2048*2;    // attention out

  cast_f32_bf16<<<4194304/256, 256, 0, stream>>>((const float4*)x, xb, 4194304);
  transpose_cast<<<dim3(64,64), 256, 0, stream>>>(Wq, Wt, 2048, 2048);
  transpose_cast<<<dim3(32,64), 256, 0, stream>>>(Wk, Wt + (size_t)2048*2048, 2048, 1024);
  transpose_cast<<<dim3(32,64), 256, 0, stream>>>(Wv, Wt + (size_t)3072*2048, 2048, 1024);
  transpose_cast<<<dim3(64,64), 256, 0, stream>>>(Wo, Wot, 2048, 2048);
  gemm_bt<true ><<<dim3(32,64), 256, 0, stream>>>(xb, Wt, QKV, 8192, 4096, 2048);
  rope_kernel<<<8192, 256, 0, stream>>>(QKV, cs, sn, Qr, Kr);
  v_transpose<<<dim3(64,4,32), 256, 0, stream>>>(QKV, Vtb);
  attn_kernel<<<dim3(32,32), 256, 0, stream>>>(Qr, Kr, Vtb, attnb);
  gemm_bt<false><<<dim3(16,64), 256, 0, stream>>>(attnb, Wot, out, 8192, 2048, 2048);
}

// Round 5
// 714.569 us; speedup vs baseline: 1.6059x; 1.0477x over previous
//
#include <hip/hip_runtime.h>
#include <stdint.h>

using bf16   = __bf16;
using bf16x4 = __attribute__((ext_vector_type(4))) __bf16;
using bf16x8 = __attribute__((ext_vector_type(8))) __bf16;
using f32x4  = __attribute__((ext_vector_type(4))) float;

#define DEV_INLINE __device__ __forceinline__

// async global->LDS, 16B per lane. LDS base must be wave-uniform; HW adds lane*16.
DEV_INLINE void gload16(const void* g, const void* l) {
  __builtin_amdgcn_global_load_lds(
      (const __attribute__((address_space(1))) unsigned int*)(uintptr_t)g,
      (__attribute__((address_space(3))) unsigned int*)(unsigned int)(uintptr_t)l,
      16, 0, 0);
}

DEV_INLINE f32x4 mfma16(bf16x8 a, bf16x8 b, f32x4 c) {
  return __builtin_amdgcn_mfma_f32_16x16x32_bf16(a, b, c, 0, 0, 0);
}

// ---------------- cast x (fp32 -> bf16) ----------------
__global__ void cast_f32_bf16(const float4* __restrict__ in, bf16* __restrict__ out, int n4) {
  int i = blockIdx.x * 256 + threadIdx.x;
  if (i >= n4) return;
  float4 v = in[i];
  bf16x4 o = { (bf16)v.x, (bf16)v.y, (bf16)v.z, (bf16)v.w };
  *(bf16x4*)(out + (size_t)i * 4) = o;
}

// ---------------- transpose+cast: in [rows][cols] f32 -> out [cols][rows] bf16 ----
__global__ void transpose_cast(const float* __restrict__ in, bf16* __restrict__ out,
                               int rows, int cols) {
  __shared__ float tile[32][33];
  int c0 = blockIdx.x * 32, r0 = blockIdx.y * 32;
  int t = threadIdx.x, tc = t & 31, tr = t >> 5;
  for (int i = 0; i < 4; ++i)
    tile[tr + i*8][tc] = in[(size_t)(r0 + tr + i*8) * cols + (c0 + tc)];
  __syncthreads();
  for (int i = 0; i < 4; ++i)
    out[(size_t)(c0 + tr + i*8) * rows + (r0 + tc)] = (bf16)tile[tc][tr + i*8];
}

// ---------------- plain GEMM (used for out-proj): C = A * Bt^T ----------------
template<bool OUT_BF16>
__global__ __launch_bounds__(256)
void gemm_bt(const bf16* __restrict__ A, const bf16* __restrict__ Bt,
             void* __restrict__ Cout, int M, int N, int K) {
  __shared__ bf16 sA[16 * 512];   // 16KB
  __shared__ bf16 sB[16 * 512];   // 16KB
  int tid = threadIdx.x;
  int w = tid >> 6, l = tid & 63, lr = l & 15, lc = l >> 4;
  int bn0 = blockIdx.x * 128, bm0 = blockIdx.y * 128;
  int wm = (w & 1) * 4, wn = (w >> 1) * 4;   // units of 16-wide tiles
  const bf16* Ab = A  + (size_t)bm0 * K;
  const bf16* Bb = Bt + (size_t)bn0 * K;
  f32x4 acc[4][4] = {};
  for (int k0 = 0; k0 < K; k0 += 64) {
    __syncthreads();
    for (int i = 0; i < 4; ++i) {
      int id = w * 4 + i;
      int mt = id >> 1, ks = id & 1;
      gload16(Ab + (size_t)(mt*16 + lr) * K + (k0 + ks*32 + lc*8), sA + id * 512);
      gload16(Bb + (size_t)(mt*16 + lr) * K + (k0 + ks*32 + lc*8), sB + id * 512);
    }
    __syncthreads();
    for (int ks = 0; ks < 2; ++ks) {
      bf16x8 af[4], bfr[4];
      for (int i = 0; i < 4; ++i)
        af[i]  = *(const bf16x8*)(sA + ((wm + i)*2 + ks) * 512 + l*8);
      for (int j = 0; j < 4; ++j)
        bfr[j] = *(const bf16x8*)(sB + ((wn + j)*2 + ks) * 512 + l*8);
      for (int i = 0; i < 4; ++i)
        for (int j = 0; j < 4; ++j)
          acc[i][j] = mfma16(af[i], bfr[j], acc[i][j]);
    }
  }
  int wrow = bm0 + wm*16, wcol = bn0 + wn*16;
  for (int i = 0; i < 4; ++i)
    for (int j = 0; j < 4; ++j)
      for (int r = 0; r < 4; ++r) {
        size_t idx = (size_t)(wrow + i*16 + lc*4 + r) * N + (wcol + j*16 + lr);
        if (OUT_BF16) ((bf16*)Cout)[idx] = (bf16)acc[i][j][r];
        else          ((float*)Cout)[idx] = acc[i][j][r];
      }
}

// ---------------- QKV GEMM with fused RoPE epilogue ----------------
// M=8192 (b*2048+s), N=4096 (16 Q heads | 8 K heads | 8 V heads), K=2048.
// Wave N-tile map {wnb, wnb+1, wnb+4, wnb+5} puts the rotate-half pair
// (d, d+64) in the same wave: lo=acc[i][j], hi=acc[i][j+2] (j=0,1).
// cos[d+64]==cos[d] (tables are concat(freqs,freqs)) so only d<64 is read.
// Q gets log2e/sqrt(128) folded in (attention uses exp2 directly).
__global__ __launch_bounds__(256)
void gemm_rope(const bf16* __restrict__ A, const bf16* __restrict__ Bt,
               const float* __restrict__ cs, const float* __restrict__ sn,
               bf16* __restrict__ Qr, bf16* __restrict__ Kr,
               bf16* __restrict__ Vbuf) {
  const int K = 2048;
  __shared__ bf16 sA[16 * 512];
  __shared__ bf16 sB[16 * 512];
  int tid = threadIdx.x;
  int w = tid >> 6, l = tid & 63, lr = l & 15, lc = l >> 4;
  int n0 = blockIdx.x;                 // N-tile-128 index: head id
  int bm0 = blockIdx.y * 128;
  int wm = (w & 1) * 4, wnb = (w >> 1) * 2;
  const bf16* Ab = A  + (size_t)bm0 * K;
  const bf16* Bb = Bt + (size_t)n0 * 128 * K;
  f32x4 acc[4][4] = {};
  for (int k0 = 0; k0 < K; k0 += 64) {
    __syncthreads();
    for (int i = 0; i < 4; ++i) {
      int id = w * 4 + i;
      int mt = id >> 1, ks = id & 1;
      gload16(Ab + (size_t)(mt*16 + lr) * K + (k0 + ks*32 + lc*8), sA + id * 512);
      gload16(Bb + (size_t)(mt*16 + lr) * K + (k0 + ks*32 + lc*8), sB + id * 512);
    }
    __syncthreads();
    for (int ks = 0; ks < 2; ++ks) {
      bf16x8 af[4], bfr[4];
      for (int i = 0; i < 4; ++i)
        af[i]  = *(const bf16x8*)(sA + ((wm + i)*2 + ks) * 512 + l*8);
      for (int j = 0; j < 4; ++j) {
        int tj = wnb + (j & 1) + (j >> 1) * 4;
        bfr[j] = *(const bf16x8*)(sB + (tj*2 + ks) * 512 + l*8);
      }
      for (int i = 0; i < 4; ++i)
        for (int j = 0; j < 4; ++j)
          acc[i][j] = mfma16(af[i], bfr[j], acc[i][j]);
    }
  }
  int b = bm0 >> 11;
  int s0loc = bm0 & 2047;
  if (n0 < 24) {
    // RoPE path: Q (n0<16) or K
    const float scale = (n0 < 16) ? 0.08838834764831845f * 1.4426950408889634f : 1.0f;
    bf16* dstBase = (n0 < 16)
        ? Qr + (size_t)(b*16 + n0) * 2048 * 128
        : Kr + (size_t)(b*8 + (n0 - 16)) * 2048 * 128;
    for (int i = 0; i < 4; ++i)
      for (int j = 0; j < 2; ++j) {
        int dlo = (wnb + j) * 16 + lr;                 // < 64
        for (int r = 0; r < 4; ++r) {
          int s = s0loc + (wm + i)*16 + lc*4 + r;
          float c  = cs[s*128 + dlo];
          float sv = sn[s*128 + dlo];
          float lo = acc[i][j][r], hi = acc[i][j+2][r];
          bf16* dst = dstBase + (size_t)s * 128;
          dst[dlo]      = (bf16)((lo*c - hi*sv) * scale);
          dst[dlo + 64] = (bf16)((hi*c + lo*sv) * scale);
        }
      }
  } else {
    // V path: plain store, Vbuf[b*2048+s][kvh*128+d]
    bf16* dstBase = Vbuf + (size_t)bm0 * 1024 + (n0 - 24) * 128;
    for (int i = 0; i < 4; ++i)
      for (int j = 0; j < 4; ++j) {
        int d = ((wnb + (j & 1) + (j >> 1) * 4)) * 16 + lr;
        for (int r = 0; r < 4; ++r) {
          int srow = (wm + i)*16 + lc*4 + r;
          dstBase[(size_t)srow * 1024 + d] = (bf16)acc[i][j][r];
        }
      }
  }
}

// ---------------- V transpose: Vbuf[b*2048+s][kvh*128+d] -> Vt[b*8+h][d][s] ----
__global__ void v_transpose(const bf16* __restrict__ Vbuf, bf16* __restrict__ Vt) {
  __shared__ bf16 tile[32][33];
  int s0 = blockIdx.x * 32, d0 = blockIdx.y * 32, bh = blockIdx.z;
  int b = bh >> 3, h = bh & 7;
  int t = threadIdx.x, tc = t & 31, tr = t >> 5;
  for (int i = 0; i < 4; ++i)
    tile[tr + i*8][tc] =
        Vbuf[((size_t)(b*2048) + s0 + tr + i*8) * 1024 + h*128 + d0 + tc];
  __syncthreads();
  for (int i = 0; i < 4; ++i)
    Vt[((size_t)bh * 128 + d0 + tr + i*8) * 2048 + s0 + tc] = tile[tc][tr + i*8];
}

// ---------------- flash attention, causal, GQA-fused, BN=128 ----------------
// block = 4 waves; both q-heads of one kv-head; BM=64 q rows, BN=128 keys/tile.
// 64KB K+V staged per barrier (halves drain count vs BN=64). P one head at a
// time in 16KB LDS; pf0/pf1 register-resident so V frags are read once.
// LDS 32+32+16=80KB -> 2 blocks/CU, matching the (256,2) register bound.
__global__ __launch_bounds__(256, 2)
void attn_kernel(const bf16* __restrict__ Q, const bf16* __restrict__ Kg,
                 const bf16* __restrict__ Vt, bf16* __restrict__ Og) {
  __shared__ bf16 sK[32 * 512];    // 32KB: chunks (nt 0..7)x(ks 0..3)
  __shared__ bf16 sV[32 * 512];    // 32KB: chunks (ntd 0..7)x(ksk 0..3)
  __shared__ bf16 sP[4 * 2048];    // 16KB: per-wave [16 q][128 key], XOR swizzle
  int qi = 31 - blockIdx.x;        // LPT: longest first
  int bkv = blockIdx.y;            // b*8 + kvh
  int b = bkv >> 3, kvh = bkv & 7;
  int tid = threadIdx.x, w = tid >> 6, l = tid & 63, lr = l & 15, lc = l >> 4;
  const bf16* Qb0 = Q + ((size_t)(b*16 + kvh*2) * 2048 + qi*64) * 128;
  const bf16* Qb1 = Qb0 + (size_t)2048 * 128;
  const bf16* Kb  = Kg + (size_t)bkv * 2048 * 128;
  const bf16* Vb  = Vt + (size_t)bkv * 128 * 2048;
  bf16x8 qf0[4], qf1[4];
  for (int ks = 0; ks < 4; ++ks) {
    size_t off = (size_t)(w*16 + lr) * 128 + ks*32 + lc*8;
    qf0[ks] = *(const bf16x8*)(Qb0 + off);
    qf1[ks] = *(const bf16x8*)(Qb1 + off);
  }
  f32x4 o0[8] = {}, o1[8] = {};
  float l0[4] = {0.f,0.f,0.f,0.f}, l1[4] = {0.f,0.f,0.f,0.f};
  int qrow = qi*64 + w*16 + lc*4;      // + r
  bf16* sPw = sP + w * 2048;
  int tmax = (qi + 2) >> 1;            // ceil((qi*64+64)/128); last key read = 2047
  for (int t = 0; t < tmax; ++t) {
    __syncthreads();
    for (int i = 0; i < 8; ++i) {
      int id = w*8 + i;
      int nt = id >> 2, ks = id & 3;
      gload16(Kb + (size_t)(t*128 + nt*16 + lr) * 128 + ks*32 + lc*8, sK + id*512);
      gload16(Vb + (size_t)(nt*16 + lr) * 2048 + t*128 + ks*32 + lc*8, sV + id*512);
    }
    __syncthreads();
    // S = Q K^T for both heads; K fragments loaded once
    f32x4 s0[8] = {}, s1[8] = {};
    for (int nt = 0; nt < 8; ++nt)
      for (int ks = 0; ks < 4; ++ks) {
        bf16x8 kf = *(const bf16x8*)(sK + (nt*4 + ks)*512 + l*8);
        s0[nt] = mfma16(qf0[ks], kf, s0[nt]);
        s1[nt] = mfma16(qf1[ks], kf, s1[nt]);
      }
    // causal mask: only the last tile needs it (block-uniform branch)
    if (t == tmax - 1) {
      for (int nt = 0; nt < 8; ++nt) {
        int col = t*128 + nt*16 + lr;
        for (int r = 0; r < 4; ++r)
          if (col > qrow + r) { s0[nt][r] = -1e30f; s1[nt][r] = -1e30f; }
      }
    }
    // P swizzle: addr = (key>>6)*1024 + q*64 + (((key>>3)&7 ^ (q&7))*8) + (key&7)
    bf16x8 pf0[4], pf1[4];
    // head 0
    for (int nt = 0; nt < 8; ++nt) {
      int hi6 = (nt >> 2) * 1024;
      int blk = (nt*2 + (lr >> 3)) & 7;
      int off = lr & 7;
      for (int r = 0; r < 4; ++r) {
        int q = lc*4 + r;
        float p = __builtin_amdgcn_exp2f(s0[nt][r]);
        l0[r] += p;
        sPw[hi6 + q*64 + ((blk ^ (q & 7)) * 8) + off] = (bf16)p;
      }
    }
    asm volatile("s_waitcnt lgkmcnt(0)" ::: "memory");
    for (int ks = 0; ks < 4; ++ks)
      pf0[ks] = *(const bf16x8*)(sPw + (ks >> 1)*1024 + lr*64 +
                                 ((((ks & 1)*4 + lc) ^ (lr & 7)) * 8));
    asm volatile("s_waitcnt lgkmcnt(0)" ::: "memory");  // reads done before overwrite
    // head 1 (reuses sPw)
    for (int nt = 0; nt < 8; ++nt) {
      int hi6 = (nt >> 2) * 1024;
      int blk = (nt*2 + (lr >> 3)) & 7;
      int off = lr & 7;
      for (int r = 0; r < 4; ++r) {
        int q = lc*4 + r;
        float p = __builtin_amdgcn_exp2f(s1[nt][r]);
        l1[r] += p;
        sPw[hi6 + q*64 + ((blk ^ (q & 7)) * 8) + off] = (bf16)p;
      }
    }
    asm volatile("s_waitcnt lgkmcnt(0)" ::: "memory");
    for (int ks = 0; ks < 4; ++ks)
      pf1[ks] = *(const bf16x8*)(sPw + (ks >> 1)*1024 + lr*64 +
                                 ((((ks & 1)*4 + lc) ^ (lr & 7)) * 8));
    // PV: V fragments read once, feed both heads
    for (int nt = 0; nt < 8; ++nt)
      for (int ks = 0; ks < 4; ++ks) {
        bf16x8 vf = *(const bf16x8*)(sV + (nt*4 + ks)*512 + l*8);
        o0[nt] = mfma16(pf0[ks], vf, o0[nt]);
        o1[nt] = mfma16(pf1[ks], vf, o1[nt]);
      }
  }
  // deferred l reduction: one shuffle ladder for the whole kernel
  for (int msk = 1; msk < 16; msk <<= 1)
    for (int r = 0; r < 4; ++r) {
      l0[r] += __shfl_xor(l0[r], msk, 64);
      l1[r] += __shfl_xor(l1[r], msk, 64);
    }
  for (int r = 0; r < 4; ++r) {
    float inv0 = 1.f / l0[r];
    float inv1 = 1.f / l1[r];
    size_t row = (size_t)(b*2048) + qi*64 + w*16 + lc*4 + r;
    size_t base0 = row * 2048 + (kvh*2) * 128;
    for (int nt = 0; nt < 8; ++nt) {
      Og[base0 + nt*16 + lr]       = (bf16)(o0[nt][r] * inv0);
      Og[base0 + 128 + nt*16 + lr] = (bf16)(o1[nt][r] * inv1);
    }
  }
}

extern "C" void kernel_launch(void* const* d_in, const int* in_sizes, int n_in,
                              void* d_out, int out_size, void* d_ws, size_t ws_size,
                              hipStream_t stream) {
  (void)in_sizes; (void)n_in; (void)out_size; (void)ws_size;
  const float* x  = (const float*)d_in[0];
  const float* cs = (const float*)d_in[1];
  const float* sn = (const float*)d_in[2];
  const float* Wq = (const float*)d_in[3];
  const float* Wk = (const float*)d_in[4];
  const float* Wv = (const float*)d_in[5];
  const float* Wo = (const float*)d_in[6];
  float* out = (float*)d_out;

  char* p = (char*)d_ws;
  bf16* xb    = (bf16*)p;  p += (size_t)8192*2048*2;    // x bf16
  bf16* Wt    = (bf16*)p;  p += (size_t)4096*2048*2;    // [Wq|Wk|Wv]^T bf16
  bf16* Wot   = (bf16*)p;  p += (size_t)2048*2048*2;    // Wo^T bf16
  bf16* Qr    = (bf16*)p;  p += (size_t)64*2048*128*2;  // Q roped [bh][s][d]
  bf16* Kr    = (bf16*)p;  p += (size_t)32*2048*128*2;  // K roped [bkv][s][d]
  bf16* Vbuf  = (bf16*)p;  p += (size_t)8192*1024*2;    // V [b*2048+s][kvh*128+d]
  bf16* Vtb   = (bf16*)p;  p += (size_t)32*2048*128*2;  // V^T [bkv][d][s]
  bf16* attnb = (bf16*)p;  p += (size_t)8192*2048*2;    // attention out

  cast_f32_bf16<<<4194304/256, 256, 0, stream>>>((const float4*)x, xb, 4194304);
  transpose_cast<<<dim3(64,64), 256, 0, stream>>>(Wq, Wt, 2048, 2048);
  transpose_cast<<<dim3(32,64), 256, 0, stream>>>(Wk, Wt + (size_t)2048*2048, 2048, 1024);
  transpose_cast<<<dim3(32,64), 256, 0, stream>>>(Wv, Wt + (size_t)3072*2048, 2048, 1024);
  transpose_cast<<<dim3(64,64), 256, 0, stream>>>(Wo, Wot, 2048, 2048);
  gemm_rope<<<dim3(32,64), 256, 0, stream>>>(xb, Wt, cs, sn, Qr, Kr, Vbuf);
  v_transpose<<<dim3(64,4,32), 256, 0, stream>>>(Vbuf, Vtb);
  attn_kernel<<<dim3(32,32), 256, 0, stream>>>(Qr, Kr, Vtb, attnb);
  gemm_bt<false><<<dim3(16,64), 256, 0, stream>>>(attnb, Wot, out, 8192, 2048, 2048);
}